// Round 2
// baseline (1761.982 us; speedup 1.0000x reference)
//
#include <hip/hip_runtime.h>
#include <hip/hip_bf16.h>
#include <cstdint>

typedef __attribute__((ext_vector_type(8))) short short8;   // 8 bf16 = 4 VGPRs
typedef __attribute__((ext_vector_type(4))) float floatx4;  // 4 fp32 acc

#define LEAKY_ALPHA 0.2f

__device__ __forceinline__ unsigned short f2bf_rne(float f) {
    unsigned u = __float_as_uint(f);
    unsigned r = u + 0x7FFFu + ((u >> 16) & 1u);   // round-to-nearest-even
    return (unsigned short)(r >> 16);
}

// ---------------------------------------------------------------------------
// Kernel 1: h = inp @ W  (fp32), s1 = h·a1, s2 = h·a2, and hT bf16 [b][o][n]
// grid 512 (8 b × 64 row-tiles of 64), block 256 (4 waves; wave handles 16 rows)
// ---------------------------------------------------------------------------
__global__ __launch_bounds__(256) void k_h(const float* __restrict__ inp,
                                           const float* __restrict__ W,
                                           const float* __restrict__ a,
                                           unsigned short* __restrict__ hT,
                                           float* __restrict__ s1,
                                           float* __restrict__ s2) {
    __shared__ float hs[64][65];   // +1 pad
    const int tid  = threadIdx.x;
    const int wv   = tid >> 6;
    const int lane = tid & 63;
    const int blk  = blockIdx.x;
    const int b     = blk >> 6;         // 0..7
    const int ibase = (blk & 63) * 64;  // row tile base

    const float a1 = a[lane];
    const float a2 = a[64 + lane];

    for (int rr = 0; rr < 16; ++rr) {
        const int rloc = wv * 16 + rr;
        const int row  = ibase + rloc;
        const float* ip = inp + ((size_t)(b * 4096 + row)) * 128;  // wave-uniform
        float acc = 0.f;
        #pragma unroll
        for (int f = 0; f < 128; f += 4) {
            float4 v = *(const float4*)(ip + f);   // uniform -> s_load
            acc += v.x * W[(f + 0) * 64 + lane];
            acc += v.y * W[(f + 1) * 64 + lane];
            acc += v.z * W[(f + 2) * 64 + lane];
            acc += v.w * W[(f + 3) * 64 + lane];
        }
        hs[rloc][lane] = acc;
        float r1 = acc * a1;
        float r2 = acc * a2;
        #pragma unroll
        for (int off = 32; off > 0; off >>= 1) {
            r1 += __shfl_xor(r1, off);
            r2 += __shfl_xor(r2, off);
        }
        if (lane == 0) {
            s1[b * 4096 + row] = r1;
            s2[b * 4096 + row] = r2;
        }
    }
    __syncthreads();

    // transpose-write hT[b][o][ibase..ibase+63] in bf16, coalesced 32 B/thread
    const int n  = tid >> 2;  // 0..63 (output col o)
    const int iq = tid & 3;   // 0..3 -> 16 i's each
    unsigned pk[8];
    #pragma unroll
    for (int s = 0; s < 16; s += 2) {
        unsigned lo = f2bf_rne(hs[iq * 16 + s    ][n]);
        unsigned hi = f2bf_rne(hs[iq * 16 + s + 1][n]);
        pk[s >> 1] = lo | (hi << 16);
    }
    unsigned short* dst = hT + ((size_t)(b * 64 + n)) * 4096 + ibase + iq * 16;
    *(int4*)(dst)     = *(int4*)&pk[0];
    *(int4*)(dst + 8) = *(int4*)&pk[4];
}

// ---------------------------------------------------------------------------
// Kernel 2: flash-style masked softmax + PV via MFMA, depth-2 prefetch ring.
// grid 1024 (8 b × 128 row-tiles of 32), block 256 = 4 waves, 4 blocks/CU.
// wave w: rows rtile*32 + (w&1)*16 .. +15, j-half = w>>1 (2048 j's, 64 steps)
// ---------------------------------------------------------------------------
__global__ __launch_bounds__(256, 4) void k_attn(const int* __restrict__ adj,
                                                 const unsigned short* __restrict__ hT,
                                                 const float* __restrict__ s1g,
                                                 const float* __restrict__ s2g,
                                                 float* __restrict__ out) {
    __shared__ float s2s[4096];
    __shared__ float accbuf[2][64][17];
    __shared__ float lbuf[2][64];

    const int tid   = threadIdx.x;
    const int b     = blockIdx.x >> 7;
    const int rtile = blockIdx.x & 127;

    {   // stage s2 row for this batch (16 KB)
        const float* src = s2g + b * 4096;
        #pragma unroll
        for (int t = 0; t < 4; ++t) {
            int idx = tid * 16 + t * 4;
            *(float4*)&s2s[idx] = *(const float4*)(src + idx);
        }
    }
    __syncthreads();

    const int wv    = tid >> 6;
    const int lane  = tid & 63;
    const int jhalf = wv >> 1;
    const int m     = lane & 15;
    const int kh    = lane >> 4;          // 0..3
    const int rbase = rtile * 32 + (wv & 1) * 16;
    const int row   = rbase + m;

    const float s1v = s1g[b * 4096 + row];
    const int jb0 = jhalf * 2048 + kh * 8;
    const int* adjrow = adj + ((size_t)(b * 4096 + row)) * 4096 + jb0;
    const unsigned short* hrow0 = hT + ((size_t)(b * 64 +  0 + m)) * 4096 + jb0;
    const unsigned short* hrow1 = hT + ((size_t)(b * 64 + 16 + m)) * 4096 + jb0;
    const unsigned short* hrow2 = hT + ((size_t)(b * 64 + 32 + m)) * 4096 + jb0;
    const unsigned short* hrow3 = hT + ((size_t)(b * 64 + 48 + m)) * 4096 + jb0;

    floatx4 acc[4];
    #pragma unroll
    for (int f = 0; f < 4; ++f) acc[f] = (floatx4){0.f, 0.f, 0.f, 0.f};
    float lsum = 0.f;

    // depth-2 prefetch ring
    int4   ra0[2], ra1[2];
    short8 rb0[2], rb1[2], rb2[2], rb3[2];
    float4 rsa[2], rsb[2];

    #pragma unroll
    for (int p = 0; p < 2; ++p) {
        const int off = p * 32;
        ra0[p] = *(const int4*)(adjrow + off);
        ra1[p] = *(const int4*)(adjrow + off + 4);
        rb0[p] = *(const short8*)(hrow0 + off);
        rb1[p] = *(const short8*)(hrow1 + off);
        rb2[p] = *(const short8*)(hrow2 + off);
        rb3[p] = *(const short8*)(hrow3 + off);
        rsa[p] = *(const float4*)&s2s[jb0 + off];
        rsb[p] = *(const float4*)&s2s[jb0 + off + 4];
    }

    for (int step = 0; step < 64; ++step) {
        const int slot = step & 1;
        const int4   ca0 = ra0[slot], ca1 = ra1[slot];
        const short8 cb0 = rb0[slot], cb1 = rb1[slot];
        const short8 cb2 = rb2[slot], cb3 = rb3[slot];
        const float4 csa = rsa[slot], csb = rsb[slot];

        const int off = ((step + 2) & 63) * 32;   // wrap: no OOB on tail
        ra0[slot] = *(const int4*)(adjrow + off);
        ra1[slot] = *(const int4*)(adjrow + off + 4);
        rb0[slot] = *(const short8*)(hrow0 + off);
        rb1[slot] = *(const short8*)(hrow1 + off);
        rb2[slot] = *(const short8*)(hrow2 + off);
        rb3[slot] = *(const short8*)(hrow3 + off);
        rsa[slot] = *(const float4*)&s2s[jb0 + off];
        rsb[slot] = *(const float4*)&s2s[jb0 + off + 4];

        const int   av[8] = {ca0.x, ca0.y, ca0.z, ca0.w, ca1.x, ca1.y, ca1.z, ca1.w};
        const float sv[8] = {csa.x, csa.y, csa.z, csa.w, csb.x, csb.y, csb.z, csb.w};

        short8 af;
        float psum = 0.f;
        #pragma unroll
        for (int t = 0; t < 8; ++t) {
            float e = s1v + sv[t];
            e = fmaxf(e, LEAKY_ALPHA * e);                 // leaky relu, 2 VALU
            float pv = (av[t] > 0) ? __expf(e) : 0.f;      // e bounded: no max-sub
            psum += pv;
            af[t] = (short)f2bf_rne(pv);
        }
        lsum += psum;

        acc[0] = __builtin_amdgcn_mfma_f32_16x16x32_bf16(af, cb0, acc[0], 0, 0, 0);
        acc[1] = __builtin_amdgcn_mfma_f32_16x16x32_bf16(af, cb1, acc[1], 0, 0, 0);
        acc[2] = __builtin_amdgcn_mfma_f32_16x16x32_bf16(af, cb2, acc[2], 0, 0, 0);
        acc[3] = __builtin_amdgcn_mfma_f32_16x16x32_bf16(af, cb3, acc[3], 0, 0, 0);
    }

    // reduce rowsum across the 4 kh-groups
    lsum += __shfl_xor(lsum, 16);
    lsum += __shfl_xor(lsum, 32);

    // combine j-halves: waves 2,3 hand off to waves 0,1
    if (wv >= 2) {
        #pragma unroll
        for (int f = 0; f < 4; ++f)
            #pragma unroll
            for (int r = 0; r < 4; ++r)
                accbuf[wv - 2][lane][f * 4 + r] = acc[f][r];
        lbuf[wv - 2][lane] = lsum;
    }
    __syncthreads();
    if (wv < 2) {
        const float ltot = lsum + lbuf[wv][lane];
        #pragma unroll
        for (int f = 0; f < 4; ++f) {
            #pragma unroll
            for (int r = 0; r < 4; ++r) {
                float v = acc[f][r] + accbuf[wv][lane][f * 4 + r];
                const int drow = (lane >> 4) * 4 + r;       // C/D layout row
                const float lr = __shfl(ltot, drow);
                const float hp = v / lr;
                const float o  = (hp > 0.f) ? hp : (__expf(hp) - 1.f);  // elu
                out[((size_t)(b * 4096 + rbase + drow)) * 64 + f * 16 + (lane & 15)] = o;
            }
        }
    }
}

// ---------------------------------------------------------------------------
extern "C" void kernel_launch(void* const* d_in, const int* in_sizes, int n_in,
                              void* d_out, int out_size, void* d_ws, size_t ws_size,
                              hipStream_t stream) {
    const float* inp = (const float*)d_in[0];   // (8,4096,128) fp32
    const int*   adj = (const int*)d_in[1];     // (8,4096,4096) int32
    const float* W   = (const float*)d_in[2];   // (128,64) fp32
    const float* a   = (const float*)d_in[3];   // (128,1) fp32
    float* out = (float*)d_out;                 // (8,4096,64) fp32

    unsigned short* hT = (unsigned short*)d_ws;                    // 4 MiB bf16
    float* s1 = (float*)((char*)d_ws + (size_t)8 * 64 * 4096 * 2); // 128 KB
    float* s2 = s1 + 8 * 4096;                                     // 128 KB

    k_h<<<512, 256, 0, stream>>>(inp, W, a, hT, s1, s2);
    k_attn<<<1024, 256, 0, stream>>>(adj, hT, s1, s2, out);
}

// Round 3
// 902.212 us; speedup vs baseline: 1.9530x; 1.9530x over previous
//
#include <hip/hip_runtime.h>
#include <hip/hip_bf16.h>
#include <cstdint>

typedef __attribute__((ext_vector_type(8))) short short8;   // 8 bf16 = 4 VGPRs
typedef __attribute__((ext_vector_type(4))) float floatx4;  // 4 fp32 acc

#define LEAKY_ALPHA 0.2f

__device__ __forceinline__ unsigned short f2bf_rne(float f) {
    unsigned u = __float_as_uint(f);
    unsigned r = u + 0x7FFFu + ((u >> 16) & 1u);   // round-to-nearest-even
    return (unsigned short)(r >> 16);
}

// ---------------------------------------------------------------------------
// Kernel 1: h = inp @ W  (fp32), s1 = h·a1, s2 = h·a2, and hT bf16 [b][o][n]
// ---------------------------------------------------------------------------
__global__ __launch_bounds__(256) void k_h(const float* __restrict__ inp,
                                           const float* __restrict__ W,
                                           const float* __restrict__ a,
                                           unsigned short* __restrict__ hT,
                                           float* __restrict__ s1,
                                           float* __restrict__ s2) {
    __shared__ float hs[64][65];   // +1 pad
    const int tid  = threadIdx.x;
    const int wv   = tid >> 6;
    const int lane = tid & 63;
    const int blk  = blockIdx.x;
    const int b     = blk >> 6;         // 0..7
    const int ibase = (blk & 63) * 64;  // row tile base

    const float a1 = a[lane];
    const float a2 = a[64 + lane];

    for (int rr = 0; rr < 16; ++rr) {
        const int rloc = wv * 16 + rr;
        const int row  = ibase + rloc;
        const float* ip = inp + ((size_t)(b * 4096 + row)) * 128;  // wave-uniform
        float acc = 0.f;
        #pragma unroll
        for (int f = 0; f < 128; f += 4) {
            float4 v = *(const float4*)(ip + f);   // uniform -> s_load
            acc += v.x * W[(f + 0) * 64 + lane];
            acc += v.y * W[(f + 1) * 64 + lane];
            acc += v.z * W[(f + 2) * 64 + lane];
            acc += v.w * W[(f + 3) * 64 + lane];
        }
        hs[rloc][lane] = acc;
        float r1 = acc * a1;
        float r2 = acc * a2;
        #pragma unroll
        for (int off = 32; off > 0; off >>= 1) {
            r1 += __shfl_xor(r1, off);
            r2 += __shfl_xor(r2, off);
        }
        if (lane == 0) {
            s1[b * 4096 + row] = r1;
            s2[b * 4096 + row] = r2;
        }
    }
    __syncthreads();

    // transpose-write hT[b][o][ibase..ibase+63] in bf16, coalesced 32 B/thread
    const int n  = tid >> 2;  // 0..63 (output col o)
    const int iq = tid & 3;   // 0..3 -> 16 i's each
    unsigned pk[8];
    #pragma unroll
    for (int s = 0; s < 16; s += 2) {
        unsigned lo = f2bf_rne(hs[iq * 16 + s    ][n]);
        unsigned hi = f2bf_rne(hs[iq * 16 + s + 1][n]);
        pk[s >> 1] = lo | (hi << 16);
    }
    unsigned short* dst = hT + ((size_t)(b * 64 + n)) * 4096 + ibase + iq * 16;
    *(int4*)(dst)     = *(int4*)&pk[0];
    *(int4*)(dst + 8) = *(int4*)&pk[4];
}

// ---------------------------------------------------------------------------
// Kernel 2: flash-style masked softmax + PV via MFMA.
// Depth-2 prefetch with COMPILE-TIME ring slots (manual 2x unroll, named
// scalar ring vars) — round-2's runtime-indexed arrays spilled to scratch.
// grid 1024 (8 b × 128 row-tiles of 32), block 256 = 4 waves, 4 blocks/CU.
// ---------------------------------------------------------------------------
__global__ __launch_bounds__(256, 4) void k_attn(const int* __restrict__ adj,
                                                 const unsigned short* __restrict__ hT,
                                                 const float* __restrict__ s1g,
                                                 const float* __restrict__ s2g,
                                                 float* __restrict__ out) {
    __shared__ float s2s[4096];
    __shared__ float accbuf[2][64][17];
    __shared__ float lbuf[2][64];

    const int tid   = threadIdx.x;
    const int b     = blockIdx.x >> 7;
    const int rtile = blockIdx.x & 127;

    {   // stage s2 row for this batch (16 KB)
        const float* src = s2g + b * 4096;
        #pragma unroll
        for (int t = 0; t < 4; ++t) {
            int idx = tid * 16 + t * 4;
            *(float4*)&s2s[idx] = *(const float4*)(src + idx);
        }
    }
    __syncthreads();

    const int wv    = tid >> 6;
    const int lane  = tid & 63;
    const int jhalf = wv >> 1;
    const int m     = lane & 15;
    const int kh    = lane >> 4;          // 0..3
    const int rbase = rtile * 32 + (wv & 1) * 16;
    const int row   = rbase + m;

    const float s1v = s1g[b * 4096 + row];
    const int jb0 = jhalf * 2048 + kh * 8;
    const int* adjrow = adj + ((size_t)(b * 4096 + row)) * 4096 + jb0;
    const unsigned short* hrow0 = hT + ((size_t)(b * 64 +  0 + m)) * 4096 + jb0;
    const unsigned short* hrow1 = hT + ((size_t)(b * 64 + 16 + m)) * 4096 + jb0;
    const unsigned short* hrow2 = hT + ((size_t)(b * 64 + 32 + m)) * 4096 + jb0;
    const unsigned short* hrow3 = hT + ((size_t)(b * 64 + 48 + m)) * 4096 + jb0;

    floatx4 acc0 = (floatx4){0.f,0.f,0.f,0.f};
    floatx4 acc1 = (floatx4){0.f,0.f,0.f,0.f};
    floatx4 acc2 = (floatx4){0.f,0.f,0.f,0.f};
    floatx4 acc3 = (floatx4){0.f,0.f,0.f,0.f};
    float lsum = 0.f;

    // depth-2 ring: named scalars, slot is a compile-time macro token
    int4   ra0_0, ra1_0, ra0_1, ra1_1;
    short8 rb0_0, rb1_0, rb2_0, rb3_0, rb0_1, rb1_1, rb2_1, rb3_1;

    ra0_0 = *(const int4*)(adjrow);        ra1_0 = *(const int4*)(adjrow + 4);
    rb0_0 = *(const short8*)(hrow0);       rb1_0 = *(const short8*)(hrow1);
    rb2_0 = *(const short8*)(hrow2);       rb3_0 = *(const short8*)(hrow3);
    ra0_1 = *(const int4*)(adjrow + 32);   ra1_1 = *(const int4*)(adjrow + 36);
    rb0_1 = *(const short8*)(hrow0 + 32);  rb1_1 = *(const short8*)(hrow1 + 32);
    rb2_1 = *(const short8*)(hrow2 + 32);  rb3_1 = *(const short8*)(hrow3 + 32);

#define GAT_STEP(SL, STEPIDX)                                                  \
    do {                                                                       \
        const int4   ca0 = ra0_##SL, ca1 = ra1_##SL;                           \
        const short8 cb0 = rb0_##SL, cb1 = rb1_##SL;                           \
        const short8 cb2 = rb2_##SL, cb3 = rb3_##SL;                           \
        const int poff = (((STEPIDX) + 2) & 63) * 32;  /* wrap: no OOB tail */ \
        ra0_##SL = *(const int4*)(adjrow + poff);                              \
        ra1_##SL = *(const int4*)(adjrow + poff + 4);                          \
        rb0_##SL = *(const short8*)(hrow0 + poff);                             \
        rb1_##SL = *(const short8*)(hrow1 + poff);                             \
        rb2_##SL = *(const short8*)(hrow2 + poff);                             \
        rb3_##SL = *(const short8*)(hrow3 + poff);                             \
        const int soff = jb0 + (STEPIDX) * 32;                                 \
        const float4 csa = *(const float4*)&s2s[soff];                         \
        const float4 csb = *(const float4*)&s2s[soff + 4];                     \
        const int   av[8] = {ca0.x, ca0.y, ca0.z, ca0.w,                       \
                             ca1.x, ca1.y, ca1.z, ca1.w};                      \
        const float sv[8] = {csa.x, csa.y, csa.z, csa.w,                       \
                             csb.x, csb.y, csb.z, csb.w};                      \
        short8 af;                                                             \
        float psum = 0.f;                                                      \
        _Pragma("unroll")                                                      \
        for (int t = 0; t < 8; ++t) {                                          \
            float e = s1v + sv[t];                                             \
            e = fmaxf(e, LEAKY_ALPHA * e);                                     \
            float pv = (av[t] > 0) ? __expf(e) : 0.f;                          \
            psum += pv;                                                        \
            af[t] = (short)f2bf_rne(pv);                                       \
        }                                                                      \
        lsum += psum;                                                          \
        acc0 = __builtin_amdgcn_mfma_f32_16x16x32_bf16(af, cb0, acc0, 0,0,0);  \
        acc1 = __builtin_amdgcn_mfma_f32_16x16x32_bf16(af, cb1, acc1, 0,0,0);  \
        acc2 = __builtin_amdgcn_mfma_f32_16x16x32_bf16(af, cb2, acc2, 0,0,0);  \
        acc3 = __builtin_amdgcn_mfma_f32_16x16x32_bf16(af, cb3, acc3, 0,0,0);  \
    } while (0)

    #pragma unroll 1
    for (int it = 0; it < 32; ++it) {
        const int s0 = it * 2;
        GAT_STEP(0, s0);
        GAT_STEP(1, s0 + 1);
    }
#undef GAT_STEP

    // reduce rowsum across the 4 kh-groups
    lsum += __shfl_xor(lsum, 16);
    lsum += __shfl_xor(lsum, 32);

    floatx4 accs[4] = {acc0, acc1, acc2, acc3};

    // combine j-halves: waves 2,3 hand off to waves 0,1
    if (wv >= 2) {
        #pragma unroll
        for (int f = 0; f < 4; ++f)
            #pragma unroll
            for (int r = 0; r < 4; ++r)
                accbuf[wv - 2][lane][f * 4 + r] = accs[f][r];
        lbuf[wv - 2][lane] = lsum;
    }
    __syncthreads();
    if (wv < 2) {
        const float ltot = lsum + lbuf[wv][lane];
        #pragma unroll
        for (int f = 0; f < 4; ++f) {
            #pragma unroll
            for (int r = 0; r < 4; ++r) {
                float v = accs[f][r] + accbuf[wv][lane][f * 4 + r];
                const int drow = (lane >> 4) * 4 + r;       // C/D layout row
                const float lr = __shfl(ltot, drow);
                const float hp = v / lr;
                const float o  = (hp > 0.f) ? hp : (__expf(hp) - 1.f);  // elu
                out[((size_t)(b * 4096 + rbase + drow)) * 64 + f * 16 + (lane & 15)] = o;
            }
        }
    }
}

// ---------------------------------------------------------------------------
extern "C" void kernel_launch(void* const* d_in, const int* in_sizes, int n_in,
                              void* d_out, int out_size, void* d_ws, size_t ws_size,
                              hipStream_t stream) {
    const float* inp = (const float*)d_in[0];   // (8,4096,128) fp32
    const int*   adj = (const int*)d_in[1];     // (8,4096,4096) int32
    const float* W   = (const float*)d_in[2];   // (128,64) fp32
    const float* a   = (const float*)d_in[3];   // (128,1) fp32
    float* out = (float*)d_out;                 // (8,4096,64) fp32

    unsigned short* hT = (unsigned short*)d_ws;                    // 4 MiB bf16
    float* s1 = (float*)((char*)d_ws + (size_t)8 * 64 * 4096 * 2); // 128 KB
    float* s2 = s1 + 8 * 4096;                                     // 128 KB

    k_h<<<512, 256, 0, stream>>>(inp, W, a, hT, s1, s2);
    k_attn<<<1024, 256, 0, stream>>>(adj, hT, s1, s2, out);
}

// Round 4
// 892.403 us; speedup vs baseline: 1.9744x; 1.0110x over previous
//
#include <hip/hip_runtime.h>
#include <hip/hip_bf16.h>
#include <cstdint>

typedef __attribute__((ext_vector_type(8))) short short8;   // 8 bf16 = 4 VGPRs
typedef __attribute__((ext_vector_type(4))) float floatx4;  // 4 fp32 acc

#define LEAKY_ALPHA 0.2f

__device__ __forceinline__ unsigned short f2bf_rne(float f) {
    unsigned u = __float_as_uint(f);
    unsigned r = u + 0x7FFFu + ((u >> 16) & 1u);   // round-to-nearest-even
    return (unsigned short)(r >> 16);
}

// ---------------------------------------------------------------------------
// Kernel 0: pack adj (int32, 512 MiB) -> bitmask (16 MiB), fully sequential
// stream. Each thread: 32 consecutive ints -> 1 uint. Wave sweeps 8 KB
// contiguous -> DRAM-friendly (m13 float4-copy pattern, ~6.3 TB/s).
// ---------------------------------------------------------------------------
__global__ __launch_bounds__(256) void k_pack(const int* __restrict__ adj,
                                              unsigned* __restrict__ mask) {
    const size_t t = (size_t)blockIdx.x * 256 + threadIdx.x;
    const int* p = adj + t * 32;
    unsigned m = 0;
    #pragma unroll
    for (int k = 0; k < 8; ++k) {
        const int4 v = *(const int4*)(p + k * 4);
        m |= (v.x > 0 ? 1u : 0u) << (k * 4 + 0);
        m |= (v.y > 0 ? 1u : 0u) << (k * 4 + 1);
        m |= (v.z > 0 ? 1u : 0u) << (k * 4 + 2);
        m |= (v.w > 0 ? 1u : 0u) << (k * 4 + 3);
    }
    mask[t] = m;
}

// ---------------------------------------------------------------------------
// Kernel 1: h = inp @ W  (fp32), s1 = h·a1, s2 = h·a2, and hT bf16 [b][o][n]
// ---------------------------------------------------------------------------
__global__ __launch_bounds__(256) void k_h(const float* __restrict__ inp,
                                           const float* __restrict__ W,
                                           const float* __restrict__ a,
                                           unsigned short* __restrict__ hT,
                                           float* __restrict__ s1,
                                           float* __restrict__ s2) {
    __shared__ float hs[64][65];   // +1 pad
    const int tid  = threadIdx.x;
    const int wv   = tid >> 6;
    const int lane = tid & 63;
    const int blk  = blockIdx.x;
    const int b     = blk >> 6;         // 0..7
    const int ibase = (blk & 63) * 64;  // row tile base

    const float a1 = a[lane];
    const float a2 = a[64 + lane];

    for (int rr = 0; rr < 16; ++rr) {
        const int rloc = wv * 16 + rr;
        const int row  = ibase + rloc;
        const float* ip = inp + ((size_t)(b * 4096 + row)) * 128;  // wave-uniform
        float acc = 0.f;
        #pragma unroll
        for (int f = 0; f < 128; f += 4) {
            float4 v = *(const float4*)(ip + f);   // uniform -> s_load
            acc += v.x * W[(f + 0) * 64 + lane];
            acc += v.y * W[(f + 1) * 64 + lane];
            acc += v.z * W[(f + 2) * 64 + lane];
            acc += v.w * W[(f + 3) * 64 + lane];
        }
        hs[rloc][lane] = acc;
        float r1 = acc * a1;
        float r2 = acc * a2;
        #pragma unroll
        for (int off = 32; off > 0; off >>= 1) {
            r1 += __shfl_xor(r1, off);
            r2 += __shfl_xor(r2, off);
        }
        if (lane == 0) {
            s1[b * 4096 + row] = r1;
            s2[b * 4096 + row] = r2;
        }
    }
    __syncthreads();

    // transpose-write hT[b][o][ibase..ibase+63] in bf16, coalesced 32 B/thread
    const int n  = tid >> 2;  // 0..63 (output col o)
    const int iq = tid & 3;   // 0..3 -> 16 i's each
    unsigned pk[8];
    #pragma unroll
    for (int s = 0; s < 16; s += 2) {
        unsigned lo = f2bf_rne(hs[iq * 16 + s    ][n]);
        unsigned hi = f2bf_rne(hs[iq * 16 + s + 1][n]);
        pk[s >> 1] = lo | (hi << 16);
    }
    unsigned short* dst = hT + ((size_t)(b * 64 + n)) * 4096 + ibase + iq * 16;
    *(int4*)(dst)     = *(int4*)&pk[0];
    *(int4*)(dst + 8) = *(int4*)&pk[4];
}

// ---------------------------------------------------------------------------
// Kernel 2: flash-style masked softmax + PV via MFMA.
// Hot loop has ZERO HBM traffic: adjacency comes from the packed bitmask
// (L2/L3-resident, one dword/lane/step), hT streams from L2, s2 from LDS.
// grid 1024 (8 b × 128 row-tiles of 32), block 256 = 4 waves, 4 blocks/CU.
// ---------------------------------------------------------------------------
__global__ __launch_bounds__(256, 4) void k_attn(const unsigned* __restrict__ mask,
                                                 const unsigned short* __restrict__ hT,
                                                 const float* __restrict__ s1g,
                                                 const float* __restrict__ s2g,
                                                 float* __restrict__ out) {
    __shared__ float s2s[4096];
    __shared__ float accbuf[2][64][17];
    __shared__ float lbuf[2][64];

    const int tid   = threadIdx.x;
    const int b     = blockIdx.x >> 7;
    const int rtile = blockIdx.x & 127;

    {   // stage s2 row for this batch (16 KB)
        const float* src = s2g + b * 4096;
        #pragma unroll
        for (int t = 0; t < 4; ++t) {
            int idx = tid * 16 + t * 4;
            *(float4*)&s2s[idx] = *(const float4*)(src + idx);
        }
    }
    __syncthreads();

    const int wv    = tid >> 6;
    const int lane  = tid & 63;
    const int jhalf = wv >> 1;
    const int m     = lane & 15;
    const int kh    = lane >> 4;          // 0..3
    const int rbase = rtile * 32 + (wv & 1) * 16;
    const int row   = rbase + m;

    const float s1v = s1g[b * 4096 + row];
    const int jb0 = jhalf * 2048 + kh * 8;
    // mask word for (row, 32-col window s): bits kh*8+t select cols kh*8+t
    const unsigned* mrow = mask + ((size_t)(b * 4096 + row)) * 128 + jhalf * 64;
    const unsigned short* hrow0 = hT + ((size_t)(b * 64 +  0 + m)) * 4096 + jb0;
    const unsigned short* hrow1 = hT + ((size_t)(b * 64 + 16 + m)) * 4096 + jb0;
    const unsigned short* hrow2 = hT + ((size_t)(b * 64 + 32 + m)) * 4096 + jb0;
    const unsigned short* hrow3 = hT + ((size_t)(b * 64 + 48 + m)) * 4096 + jb0;

    floatx4 acc0 = (floatx4){0.f,0.f,0.f,0.f};
    floatx4 acc1 = (floatx4){0.f,0.f,0.f,0.f};
    floatx4 acc2 = (floatx4){0.f,0.f,0.f,0.f};
    floatx4 acc3 = (floatx4){0.f,0.f,0.f,0.f};
    float lsum = 0.f;

    // depth-2 ring: named scalars, slot is a compile-time macro token
    unsigned rm_0, rm_1;
    short8 rb0_0, rb1_0, rb2_0, rb3_0, rb0_1, rb1_1, rb2_1, rb3_1;

    rm_0  = mrow[0];
    rb0_0 = *(const short8*)(hrow0);       rb1_0 = *(const short8*)(hrow1);
    rb2_0 = *(const short8*)(hrow2);       rb3_0 = *(const short8*)(hrow3);
    rm_1  = mrow[1];
    rb0_1 = *(const short8*)(hrow0 + 32);  rb1_1 = *(const short8*)(hrow1 + 32);
    rb2_1 = *(const short8*)(hrow2 + 32);  rb3_1 = *(const short8*)(hrow3 + 32);

#define GAT_STEP(SL, STEPIDX)                                                  \
    do {                                                                       \
        const unsigned cmw = rm_##SL;                                          \
        const short8 cb0 = rb0_##SL, cb1 = rb1_##SL;                           \
        const short8 cb2 = rb2_##SL, cb3 = rb3_##SL;                           \
        const int pstep = ((STEPIDX) + 2) & 63;        /* wrap: no OOB tail */ \
        const int poff = pstep * 32;                                           \
        rm_##SL  = mrow[pstep];                                                \
        rb0_##SL = *(const short8*)(hrow0 + poff);                             \
        rb1_##SL = *(const short8*)(hrow1 + poff);                             \
        rb2_##SL = *(const short8*)(hrow2 + poff);                             \
        rb3_##SL = *(const short8*)(hrow3 + poff);                             \
        const int soff = jb0 + (STEPIDX) * 32;                                 \
        const float4 csa = *(const float4*)&s2s[soff];                         \
        const float4 csb = *(const float4*)&s2s[soff + 4];                     \
        const unsigned mb = (cmw >> (kh * 8)) & 0xffu;                         \
        const float sv[8] = {csa.x, csa.y, csa.z, csa.w,                       \
                             csb.x, csb.y, csb.z, csb.w};                      \
        short8 af;                                                             \
        float psum = 0.f;                                                      \
        _Pragma("unroll")                                                      \
        for (int t = 0; t < 8; ++t) {                                          \
            float e = s1v + sv[t];                                             \
            e = fmaxf(e, LEAKY_ALPHA * e);                                     \
            float pv = ((mb >> t) & 1u) ? __expf(e) : 0.f;                     \
            psum += pv;                                                        \
            af[t] = (short)f2bf_rne(pv);                                       \
        }                                                                      \
        lsum += psum;                                                          \
        acc0 = __builtin_amdgcn_mfma_f32_16x16x32_bf16(af, cb0, acc0, 0,0,0);  \
        acc1 = __builtin_amdgcn_mfma_f32_16x16x32_bf16(af, cb1, acc1, 0,0,0);  \
        acc2 = __builtin_amdgcn_mfma_f32_16x16x32_bf16(af, cb2, acc2, 0,0,0);  \
        acc3 = __builtin_amdgcn_mfma_f32_16x16x32_bf16(af, cb3, acc3, 0,0,0);  \
    } while (0)

    #pragma unroll 1
    for (int it = 0; it < 32; ++it) {
        const int s0 = it * 2;
        GAT_STEP(0, s0);
        GAT_STEP(1, s0 + 1);
    }
#undef GAT_STEP

    // reduce rowsum across the 4 kh-groups
    lsum += __shfl_xor(lsum, 16);
    lsum += __shfl_xor(lsum, 32);

    floatx4 accs[4] = {acc0, acc1, acc2, acc3};

    // combine j-halves: waves 2,3 hand off to waves 0,1
    if (wv >= 2) {
        #pragma unroll
        for (int f = 0; f < 4; ++f)
            #pragma unroll
            for (int r = 0; r < 4; ++r)
                accbuf[wv - 2][lane][f * 4 + r] = accs[f][r];
        lbuf[wv - 2][lane] = lsum;
    }
    __syncthreads();
    if (wv < 2) {
        const float ltot = lsum + lbuf[wv][lane];
        #pragma unroll
        for (int f = 0; f < 4; ++f) {
            #pragma unroll
            for (int r = 0; r < 4; ++r) {
                float v = accs[f][r] + accbuf[wv][lane][f * 4 + r];
                const int drow = (lane >> 4) * 4 + r;       // C/D layout row
                const float lr = __shfl(ltot, drow);
                const float hp = v / lr;
                const float o  = (hp > 0.f) ? hp : (__expf(hp) - 1.f);  // elu
                out[((size_t)(b * 4096 + rbase + drow)) * 64 + f * 16 + (lane & 15)] = o;
            }
        }
    }
}

// ---------------------------------------------------------------------------
extern "C" void kernel_launch(void* const* d_in, const int* in_sizes, int n_in,
                              void* d_out, int out_size, void* d_ws, size_t ws_size,
                              hipStream_t stream) {
    const float* inp = (const float*)d_in[0];   // (8,4096,128) fp32
    const int*   adj = (const int*)d_in[1];     // (8,4096,4096) int32
    const float* W   = (const float*)d_in[2];   // (128,64) fp32
    const float* a   = (const float*)d_in[3];   // (128,1) fp32
    float* out = (float*)d_out;                 // (8,4096,64) fp32

    unsigned short* hT = (unsigned short*)d_ws;                        // 4 MiB bf16
    float* s1 = (float*)((char*)d_ws + (size_t)8 * 64 * 4096 * 2);     // 128 KB
    float* s2 = s1 + 8 * 4096;                                         // 128 KB
    unsigned* mask = (unsigned*)(s2 + 8 * 4096);                       // 16 MiB

    k_pack<<<16384, 256, 0, stream>>>(adj, mask);
    k_h<<<512, 256, 0, stream>>>(inp, W, a, hT, s1, s2);
    k_attn<<<1024, 256, 0, stream>>>(mask, hT, s1, s2, out);
}

// Round 5
// 861.590 us; speedup vs baseline: 2.0450x; 1.0358x over previous
//
#include <hip/hip_runtime.h>
#include <hip/hip_bf16.h>
#include <cstdint>

typedef __attribute__((ext_vector_type(8))) short short8;   // 8 bf16 = 4 VGPRs
typedef __attribute__((ext_vector_type(4))) float floatx4;  // 4 fp32 acc

#define LEAKY_ALPHA 0.2f

__device__ __forceinline__ unsigned short f2bf_rne(float f) {
    unsigned u = __float_as_uint(f);
    unsigned r = u + 0x7FFFu + ((u >> 16) & 1u);   // round-to-nearest-even
    return (unsigned short)(r >> 16);
}

// ---------------------------------------------------------------------------
// Kernel 1: h = inp @ W  (fp32), s1 = h·a1, s2 = h·a2, and hT bf16 [b][o][n]
// ---------------------------------------------------------------------------
__global__ __launch_bounds__(256) void k_h(const float* __restrict__ inp,
                                           const float* __restrict__ W,
                                           const float* __restrict__ a,
                                           unsigned short* __restrict__ hT,
                                           float* __restrict__ s1,
                                           float* __restrict__ s2) {
    __shared__ float hs[64][65];   // +1 pad
    const int tid  = threadIdx.x;
    const int wv   = tid >> 6;
    const int lane = tid & 63;
    const int blk  = blockIdx.x;
    const int b     = blk >> 6;         // 0..7
    const int ibase = (blk & 63) * 64;  // row tile base

    const float a1 = a[lane];
    const float a2 = a[64 + lane];

    for (int rr = 0; rr < 16; ++rr) {
        const int rloc = wv * 16 + rr;
        const int row  = ibase + rloc;
        const float* ip = inp + ((size_t)(b * 4096 + row)) * 128;  // wave-uniform
        float acc = 0.f;
        #pragma unroll
        for (int f = 0; f < 128; f += 4) {
            float4 v = *(const float4*)(ip + f);   // uniform -> s_load
            acc += v.x * W[(f + 0) * 64 + lane];
            acc += v.y * W[(f + 1) * 64 + lane];
            acc += v.z * W[(f + 2) * 64 + lane];
            acc += v.w * W[(f + 3) * 64 + lane];
        }
        hs[rloc][lane] = acc;
        float r1 = acc * a1;
        float r2 = acc * a2;
        #pragma unroll
        for (int off = 32; off > 0; off >>= 1) {
            r1 += __shfl_xor(r1, off);
            r2 += __shfl_xor(r2, off);
        }
        if (lane == 0) {
            s1[b * 4096 + row] = r1;
            s2[b * 4096 + row] = r2;
        }
    }
    __syncthreads();

    // transpose-write hT[b][o][ibase..ibase+63] in bf16, coalesced 32 B/thread
    const int n  = tid >> 2;  // 0..63 (output col o)
    const int iq = tid & 3;   // 0..3 -> 16 i's each
    unsigned pk[8];
    #pragma unroll
    for (int s = 0; s < 16; s += 2) {
        unsigned lo = f2bf_rne(hs[iq * 16 + s    ][n]);
        unsigned hi = f2bf_rne(hs[iq * 16 + s + 1][n]);
        pk[s >> 1] = lo | (hi << 16);
    }
    unsigned short* dst = hT + ((size_t)(b * 64 + n)) * 4096 + ibase + iq * 16;
    *(int4*)(dst)     = *(int4*)&pk[0];
    *(int4*)(dst + 8) = *(int4*)&pk[4];
}

// ---------------------------------------------------------------------------
// Kernel 2 (FUSED): phase A streams this block's contiguous 512 KB adj slice
// sequentially (k_pack pattern) into a 16.5 KB LDS bitmask; phase B runs the
// masked-softmax + PV MFMA loop with the mask served from LDS — no cross-
// kernel L3 producer/consumer latency on the critical path.
// grid 1024 (8 b × 128 row-tiles of 32), block 256 = 4 waves, 4 blocks/CU.
// ---------------------------------------------------------------------------
__global__ __launch_bounds__(256, 4) void k_fused(const int* __restrict__ adj,
                                                  const unsigned short* __restrict__ hT,
                                                  const float* __restrict__ s1g,
                                                  const float* __restrict__ s2g,
                                                  float* __restrict__ out) {
    __shared__ unsigned maskw[32][129];   // [local row][col/32], +1 pad
    __shared__ float s2s[4096];

    const int tid   = threadIdx.x;
    const int b     = blockIdx.x >> 7;
    const int rtile = blockIdx.x & 127;
    const int wv    = tid >> 6;
    const int lane  = tid & 63;

    {   // stage s2 row for this batch (16 KB)
        const float* src = s2g + b * 4096;
        #pragma unroll
        for (int t = 0; t < 4; ++t) {
            int idx = tid * 16 + t * 4;
            *(float4*)&s2s[idx] = *(const float4*)(src + idx);
        }
    }

    // ---- Phase A: pack 512 KB contiguous adj slice -> LDS bitmask ----
    // wave wv owns 8 consecutive rows (128 KB); per iter a wave sweeps 8 KB
    // contiguous (lane reads 32 consecutive ints = one mask word).
    {
        const int* abase = adj + ((size_t)(b * 4096 + rtile * 32)) * 4096
                         + (size_t)wv * 32768;
        #pragma unroll 2
        for (int i = 0; i < 16; ++i) {
            const int* p = abase + i * 2048 + lane * 32;
            unsigned w = 0;
            #pragma unroll
            for (int k = 0; k < 8; ++k) {
                const int4 v = *(const int4*)(p + k * 4);
                w |= (v.x > 0 ? 1u : 0u) << (k * 4 + 0);
                w |= (v.y > 0 ? 1u : 0u) << (k * 4 + 1);
                w |= (v.z > 0 ? 1u : 0u) << (k * 4 + 2);
                w |= (v.w > 0 ? 1u : 0u) << (k * 4 + 3);
            }
            maskw[wv * 8 + (i >> 1)][(i & 1) * 64 + lane] = w;
        }
    }
    __syncthreads();

    // ---- Phase B: masked softmax + PV via MFMA ----
    const int jhalf = wv >> 1;
    const int m     = lane & 15;
    const int kh    = lane >> 4;          // 0..3
    const int rl    = (wv & 1) * 16 + m;  // local row 0..31
    const int rbase = rtile * 32 + (wv & 1) * 16;
    const int row   = rbase + m;

    const float s1v = s1g[b * 4096 + row];
    const int jb0 = jhalf * 2048 + kh * 8;
    const unsigned* mrow = &maskw[rl][jhalf * 64];   // LDS, word per 32 cols
    const unsigned short* hrow0 = hT + ((size_t)(b * 64 +  0 + m)) * 4096 + jb0;
    const unsigned short* hrow1 = hT + ((size_t)(b * 64 + 16 + m)) * 4096 + jb0;
    const unsigned short* hrow2 = hT + ((size_t)(b * 64 + 32 + m)) * 4096 + jb0;
    const unsigned short* hrow3 = hT + ((size_t)(b * 64 + 48 + m)) * 4096 + jb0;

    floatx4 acc0 = (floatx4){0.f,0.f,0.f,0.f};
    floatx4 acc1 = (floatx4){0.f,0.f,0.f,0.f};
    floatx4 acc2 = (floatx4){0.f,0.f,0.f,0.f};
    floatx4 acc3 = (floatx4){0.f,0.f,0.f,0.f};
    float lsum = 0.f;

    // depth-2 ring for the L2-resident hT streams; mask comes from LDS
    unsigned rm_0, rm_1;
    short8 rb0_0, rb1_0, rb2_0, rb3_0, rb0_1, rb1_1, rb2_1, rb3_1;

    rm_0  = mrow[0];
    rb0_0 = *(const short8*)(hrow0);       rb1_0 = *(const short8*)(hrow1);
    rb2_0 = *(const short8*)(hrow2);       rb3_0 = *(const short8*)(hrow3);
    rm_1  = mrow[1];
    rb0_1 = *(const short8*)(hrow0 + 32);  rb1_1 = *(const short8*)(hrow1 + 32);
    rb2_1 = *(const short8*)(hrow2 + 32);  rb3_1 = *(const short8*)(hrow3 + 32);

#define GAT_STEP(SL, STEPIDX)                                                  \
    do {                                                                       \
        const unsigned cmw = rm_##SL;                                          \
        const short8 cb0 = rb0_##SL, cb1 = rb1_##SL;                           \
        const short8 cb2 = rb2_##SL, cb3 = rb3_##SL;                           \
        const int pstep = ((STEPIDX) + 2) & 63;        /* wrap: no OOB tail */ \
        const int poff = pstep * 32;                                           \
        rm_##SL  = mrow[pstep];                                                \
        rb0_##SL = *(const short8*)(hrow0 + poff);                             \
        rb1_##SL = *(const short8*)(hrow1 + poff);                             \
        rb2_##SL = *(const short8*)(hrow2 + poff);                             \
        rb3_##SL = *(const short8*)(hrow3 + poff);                             \
        const int soff = jb0 + (STEPIDX) * 32;                                 \
        const float4 csa = *(const float4*)&s2s[soff];                         \
        const float4 csb = *(const float4*)&s2s[soff + 4];                     \
        const unsigned mb = (cmw >> (kh * 8)) & 0xffu;                         \
        const float sv[8] = {csa.x, csa.y, csa.z, csa.w,                       \
                             csb.x, csb.y, csb.z, csb.w};                      \
        short8 af;                                                             \
        float psum = 0.f;                                                      \
        _Pragma("unroll")                                                      \
        for (int t = 0; t < 8; ++t) {                                          \
            float e = s1v + sv[t];                                             \
            e = fmaxf(e, LEAKY_ALPHA * e);                                     \
            float pv = ((mb >> t) & 1u) ? __expf(e) : 0.f;                     \
            psum += pv;                                                        \
            af[t] = (short)f2bf_rne(pv);                                       \
        }                                                                      \
        lsum += psum;                                                          \
        acc0 = __builtin_amdgcn_mfma_f32_16x16x32_bf16(af, cb0, acc0, 0,0,0);  \
        acc1 = __builtin_amdgcn_mfma_f32_16x16x32_bf16(af, cb1, acc1, 0,0,0);  \
        acc2 = __builtin_amdgcn_mfma_f32_16x16x32_bf16(af, cb2, acc2, 0,0,0);  \
        acc3 = __builtin_amdgcn_mfma_f32_16x16x32_bf16(af, cb3, acc3, 0,0,0);  \
    } while (0)

    #pragma unroll 1
    for (int it = 0; it < 32; ++it) {
        const int s0 = it * 2;
        GAT_STEP(0, s0);
        GAT_STEP(1, s0 + 1);
    }
#undef GAT_STEP

    // reduce rowsum across the 4 kh-groups
    lsum += __shfl_xor(lsum, 16);
    lsum += __shfl_xor(lsum, 32);

    floatx4 accs[4] = {acc0, acc1, acc2, acc3};

    // epilogue scratch aliases the (now dead) mask LDS: [2][64][17] + [2][64]
    float* accb = (float*)&maskw[0][0];
    float* lb   = accb + 2 * 64 * 17;

    __syncthreads();   // mask no longer needed by any wave
    if (wv >= 2) {
        #pragma unroll
        for (int f = 0; f < 4; ++f)
            #pragma unroll
            for (int r = 0; r < 4; ++r)
                accb[(wv - 2) * 64 * 17 + lane * 17 + f * 4 + r] = accs[f][r];
        lb[(wv - 2) * 64 + lane] = lsum;
    }
    __syncthreads();
    if (wv < 2) {
        const float ltot = lsum + lb[wv * 64 + lane];
        #pragma unroll
        for (int f = 0; f < 4; ++f) {
            #pragma unroll
            for (int r = 0; r < 4; ++r) {
                float v = accs[f][r] + accb[wv * 64 * 17 + lane * 17 + f * 4 + r];
                const int drow = (lane >> 4) * 4 + r;       // C/D layout row
                const float lr = __shfl(ltot, drow);
                const float hp = v / lr;
                const float o  = (hp > 0.f) ? hp : (__expf(hp) - 1.f);  // elu
                out[((size_t)(b * 4096 + rbase + drow)) * 64 + f * 16 + (lane & 15)] = o;
            }
        }
    }
}

// ---------------------------------------------------------------------------
extern "C" void kernel_launch(void* const* d_in, const int* in_sizes, int n_in,
                              void* d_out, int out_size, void* d_ws, size_t ws_size,
                              hipStream_t stream) {
    const float* inp = (const float*)d_in[0];   // (8,4096,128) fp32
    const int*   adj = (const int*)d_in[1];     // (8,4096,4096) int32
    const float* W   = (const float*)d_in[2];   // (128,64) fp32
    const float* a   = (const float*)d_in[3];   // (128,1) fp32
    float* out = (float*)d_out;                 // (8,4096,64) fp32

    unsigned short* hT = (unsigned short*)d_ws;                    // 4 MiB bf16
    float* s1 = (float*)((char*)d_ws + (size_t)8 * 64 * 4096 * 2); // 128 KB
    float* s2 = s1 + 8 * 4096;                                     // 128 KB

    k_h<<<512, 256, 0, stream>>>(inp, W, a, hT, s1, s2);
    k_fused<<<1024, 256, 0, stream>>>(adj, hT, s1, s2, out);
}

// Round 6
// 812.032 us; speedup vs baseline: 2.1698x; 1.0610x over previous
//
#include <hip/hip_runtime.h>
#include <hip/hip_bf16.h>
#include <cstdint>

typedef __attribute__((ext_vector_type(8))) short short8;   // 8 bf16 = 4 VGPRs
typedef __attribute__((ext_vector_type(4))) float floatx4;  // 4 fp32 acc

#define LEAKY_ALPHA 0.2f

__device__ __forceinline__ unsigned short f2bf_rne(float f) {
    unsigned u = __float_as_uint(f);
    unsigned r = u + 0x7FFFu + ((u >> 16) & 1u);   // round-to-nearest-even
    return (unsigned short)(r >> 16);
}

// ---------------------------------------------------------------------------
// Kernel 1: h = inp @ W  (fp32), s1 = h·a1, s2 = h·a2.
// hT layout is TILED: [b][tile=n/32][o(64)][nc=n%32] bf16 — every 32-col
// K-window is one contiguous 4 KB tile, so Phase-B B-fragment loads are
// 1 KB contiguous instead of 16 rows x 8 KB stride (L2/L3 channel hotspot).
// ---------------------------------------------------------------------------
__global__ __launch_bounds__(256) void k_h(const float* __restrict__ inp,
                                           const float* __restrict__ W,
                                           const float* __restrict__ a,
                                           unsigned short* __restrict__ hT,
                                           float* __restrict__ s1,
                                           float* __restrict__ s2) {
    __shared__ float hs[64][65];   // +1 pad
    const int tid  = threadIdx.x;
    const int wv   = tid >> 6;
    const int lane = tid & 63;
    const int blk  = blockIdx.x;
    const int b     = blk >> 6;         // 0..7
    const int ibase = (blk & 63) * 64;  // row tile base

    const float a1 = a[lane];
    const float a2 = a[64 + lane];

    for (int rr = 0; rr < 16; ++rr) {
        const int rloc = wv * 16 + rr;
        const int row  = ibase + rloc;
        const float* ip = inp + ((size_t)(b * 4096 + row)) * 128;  // wave-uniform
        float acc = 0.f;
        #pragma unroll
        for (int f = 0; f < 128; f += 4) {
            float4 v = *(const float4*)(ip + f);   // uniform -> s_load
            acc += v.x * W[(f + 0) * 64 + lane];
            acc += v.y * W[(f + 1) * 64 + lane];
            acc += v.z * W[(f + 2) * 64 + lane];
            acc += v.w * W[(f + 3) * 64 + lane];
        }
        hs[rloc][lane] = acc;
        float r1 = acc * a1;
        float r2 = acc * a2;
        #pragma unroll
        for (int off = 32; off > 0; off >>= 1) {
            r1 += __shfl_xor(r1, off);
            r2 += __shfl_xor(r2, off);
        }
        if (lane == 0) {
            s1[b * 4096 + row] = r1;
            s2[b * 4096 + row] = r2;
        }
    }
    __syncthreads();

    // write tiled hT[b][tile][o][nc]: thread (o, half) writes 16 consecutive nc
    const int o    = tid & 63;
    const int half = tid >> 6;          // 0..3
    const int tl   = half >> 1;         // local tile 0..1
    const int nco  = (half & 1) * 16;   // nc offset 0 or 16
    unsigned pk[8];
    #pragma unroll
    for (int s = 0; s < 16; s += 2) {
        unsigned lo = f2bf_rne(hs[tl * 32 + nco + s    ][o]);   // row uniform, col=lane: bcast-free
        unsigned hi = f2bf_rne(hs[tl * 32 + nco + s + 1][o]);
        pk[s >> 1] = lo | (hi << 16);
    }
    const int tile = (ibase >> 5) + tl;
    unsigned short* dst = hT + (((size_t)b * 128 + tile) * 64 + o) * 32 + nco;
    *(int4*)(dst)     = *(int4*)&pk[0];
    *(int4*)(dst + 8) = *(int4*)&pk[4];
}

// ---------------------------------------------------------------------------
// Kernel 2 (FUSED): phase A packs the block's contiguous 512 KB adj slice
// into a 16.5 KB LDS bitmask; phase B: masked softmax + PV MFMA with
// sequential 4 KB-tile hT streams.
// grid 1024 (8 b × 128 row-tiles of 32), block 256 = 4 waves, 4 blocks/CU.
// ---------------------------------------------------------------------------
__global__ __launch_bounds__(256, 4) void k_fused(const int* __restrict__ adj,
                                                  const unsigned short* __restrict__ hT,
                                                  const float* __restrict__ s1g,
                                                  const float* __restrict__ s2g,
                                                  float* __restrict__ out) {
    __shared__ unsigned maskw[32][129];   // [local row][col/32], +1 pad
    __shared__ float s2s[4096];

    const int tid   = threadIdx.x;
    const int b     = blockIdx.x >> 7;
    const int rtile = blockIdx.x & 127;
    const int wv    = tid >> 6;
    const int lane  = tid & 63;

    {   // stage s2 row for this batch (16 KB)
        const float* src = s2g + b * 4096;
        #pragma unroll
        for (int t = 0; t < 4; ++t) {
            int idx = tid * 16 + t * 4;
            *(float4*)&s2s[idx] = *(const float4*)(src + idx);
        }
    }

    // ---- Phase A: pack 512 KB contiguous adj slice -> LDS bitmask ----
    {
        const int* abase = adj + ((size_t)(b * 4096 + rtile * 32)) * 4096
                         + (size_t)wv * 32768;
        #pragma unroll 2
        for (int i = 0; i < 16; ++i) {
            const int* p = abase + i * 2048 + lane * 32;
            unsigned w = 0;
            #pragma unroll
            for (int k = 0; k < 8; ++k) {
                const int4 v = *(const int4*)(p + k * 4);
                w |= (v.x > 0 ? 1u : 0u) << (k * 4 + 0);
                w |= (v.y > 0 ? 1u : 0u) << (k * 4 + 1);
                w |= (v.z > 0 ? 1u : 0u) << (k * 4 + 2);
                w |= (v.w > 0 ? 1u : 0u) << (k * 4 + 3);
            }
            maskw[wv * 8 + (i >> 1)][(i & 1) * 64 + lane] = w;
        }
    }
    __syncthreads();

    // ---- Phase B: masked softmax + PV via MFMA ----
    const int jhalf = wv >> 1;
    const int m     = lane & 15;
    const int kh    = lane >> 4;          // 0..3
    const int rl    = (wv & 1) * 16 + m;  // local row 0..31
    const int rbase = rtile * 32 + (wv & 1) * 16;
    const int row   = rbase + m;

    const float s1v = s1g[b * 4096 + row];
    const int jb0 = jhalf * 2048 + kh * 8;           // global col base for s2s
    const unsigned* mrow = &maskw[rl][jhalf * 64];   // LDS mask words

    // tiled hT: tile = jhalf*64 + step; lane reads o=16g+m, nc=kh*8..+7
    // stream base: element ((b*128 + jhalf*64)*64 + m)*32 + kh*8; +g*512; +step*2048
    const unsigned short* hbase =
        hT + (((size_t)b * 128 + jhalf * 64) * 64 + m) * 32 + kh * 8;
    const unsigned short* hrow0 = hbase;
    const unsigned short* hrow1 = hbase + 512;    // +16 o
    const unsigned short* hrow2 = hbase + 1024;   // +32 o
    const unsigned short* hrow3 = hbase + 1536;   // +48 o

    floatx4 acc0 = (floatx4){0.f,0.f,0.f,0.f};
    floatx4 acc1 = (floatx4){0.f,0.f,0.f,0.f};
    floatx4 acc2 = (floatx4){0.f,0.f,0.f,0.f};
    floatx4 acc3 = (floatx4){0.f,0.f,0.f,0.f};
    float lsum = 0.f;

    // depth-2 ring: named scalars, slot is a compile-time macro token
    unsigned rm_0, rm_1;
    short8 rb0_0, rb1_0, rb2_0, rb3_0, rb0_1, rb1_1, rb2_1, rb3_1;

    rm_0  = mrow[0];
    rb0_0 = *(const short8*)(hrow0);         rb1_0 = *(const short8*)(hrow1);
    rb2_0 = *(const short8*)(hrow2);         rb3_0 = *(const short8*)(hrow3);
    rm_1  = mrow[1];
    rb0_1 = *(const short8*)(hrow0 + 2048);  rb1_1 = *(const short8*)(hrow1 + 2048);
    rb2_1 = *(const short8*)(hrow2 + 2048);  rb3_1 = *(const short8*)(hrow3 + 2048);

#define GAT_STEP(SL, STEPIDX)                                                  \
    do {                                                                       \
        const unsigned cmw = rm_##SL;                                          \
        const short8 cb0 = rb0_##SL, cb1 = rb1_##SL;                           \
        const short8 cb2 = rb2_##SL, cb3 = rb3_##SL;                           \
        const int pstep = ((STEPIDX) + 2) & 63;        /* wrap: no OOB tail */ \
        const int poff = pstep * 2048;                 /* 4 KB tiles */        \
        rm_##SL  = mrow[pstep];                                                \
        rb0_##SL = *(const short8*)(hrow0 + poff);                             \
        rb1_##SL = *(const short8*)(hrow1 + poff);                             \
        rb2_##SL = *(const short8*)(hrow2 + poff);                             \
        rb3_##SL = *(const short8*)(hrow3 + poff);                             \
        const int soff = jb0 + (STEPIDX) * 32;                                 \
        const float4 csa = *(const float4*)&s2s[soff];                         \
        const float4 csb = *(const float4*)&s2s[soff + 4];                     \
        const unsigned mb = (cmw >> (kh * 8)) & 0xffu;                         \
        const float sv[8] = {csa.x, csa.y, csa.z, csa.w,                       \
                             csb.x, csb.y, csb.z, csb.w};                      \
        short8 af;                                                             \
        float psum = 0.f;                                                      \
        _Pragma("unroll")                                                      \
        for (int t = 0; t < 8; ++t) {                                          \
            float e = s1v + sv[t];                                             \
            e = fmaxf(e, LEAKY_ALPHA * e);                                     \
            float pv = ((mb >> t) & 1u) ? __expf(e) : 0.f;                     \
            psum += pv;                                                        \
            af[t] = (short)f2bf_rne(pv);                                       \
        }                                                                      \
        lsum += psum;                                                          \
        acc0 = __builtin_amdgcn_mfma_f32_16x16x32_bf16(af, cb0, acc0, 0,0,0);  \
        acc1 = __builtin_amdgcn_mfma_f32_16x16x32_bf16(af, cb1, acc1, 0,0,0);  \
        acc2 = __builtin_amdgcn_mfma_f32_16x16x32_bf16(af, cb2, acc2, 0,0,0);  \
        acc3 = __builtin_amdgcn_mfma_f32_16x16x32_bf16(af, cb3, acc3, 0,0,0);  \
    } while (0)

    #pragma unroll 1
    for (int it = 0; it < 32; ++it) {
        const int s0 = it * 2;
        GAT_STEP(0, s0);
        GAT_STEP(1, s0 + 1);
    }
#undef GAT_STEP

    // reduce rowsum across the 4 kh-groups
    lsum += __shfl_xor(lsum, 16);
    lsum += __shfl_xor(lsum, 32);

    floatx4 accs[4] = {acc0, acc1, acc2, acc3};

    // epilogue scratch aliases the (now dead) mask LDS: [2][64][17] + [2][64]
    float* accb = (float*)&maskw[0][0];
    float* lb   = accb + 2 * 64 * 17;

    __syncthreads();   // mask no longer needed by any wave
    if (wv >= 2) {
        #pragma unroll
        for (int f = 0; f < 4; ++f)
            #pragma unroll
            for (int r = 0; r < 4; ++r)
                accb[(wv - 2) * 64 * 17 + lane * 17 + f * 4 + r] = accs[f][r];
        lb[(wv - 2) * 64 + lane] = lsum;
    }
    __syncthreads();
    if (wv < 2) {
        const float ltot = lsum + lb[wv * 64 + lane];
        #pragma unroll
        for (int f = 0; f < 4; ++f) {
            #pragma unroll
            for (int r = 0; r < 4; ++r) {
                float v = accs[f][r] + accb[wv * 64 * 17 + lane * 17 + f * 4 + r];
                const int drow = (lane >> 4) * 4 + r;       // C/D layout row
                const float lr = __shfl(ltot, drow);
                const float hp = v / lr;
                const float o  = (hp > 0.f) ? hp : (__expf(hp) - 1.f);  // elu
                out[((size_t)(b * 4096 + rbase + drow)) * 64 + f * 16 + (lane & 15)] = o;
            }
        }
    }
}

// ---------------------------------------------------------------------------
extern "C" void kernel_launch(void* const* d_in, const int* in_sizes, int n_in,
                              void* d_out, int out_size, void* d_ws, size_t ws_size,
                              hipStream_t stream) {
    const float* inp = (const float*)d_in[0];   // (8,4096,128) fp32
    const int*   adj = (const int*)d_in[1];     // (8,4096,4096) int32
    const float* W   = (const float*)d_in[2];   // (128,64) fp32
    const float* a   = (const float*)d_in[3];   // (128,1) fp32
    float* out = (float*)d_out;                 // (8,4096,64) fp32

    unsigned short* hT = (unsigned short*)d_ws;                    // 4 MiB bf16 (tiled)
    float* s1 = (float*)((char*)d_ws + (size_t)8 * 64 * 4096 * 2); // 128 KB
    float* s2 = s1 + 8 * 4096;                                     // 128 KB

    k_h<<<512, 256, 0, stream>>>(inp, W, a, hT, s1, s2);
    k_fused<<<1024, 256, 0, stream>>>(adj, hT, s1, s2, out);
}